// Round 2
// baseline (148.924 us; speedup 1.0000x reference)
//
#include <hip/hip_runtime.h>

// Species-routed expert Linear as a bucketed grouped GEMM.
//   out[a] = rho[a] @ W[sym[a]] + b[sym[a]]   (NTA=65536, K=N=512, 4 species)
// R2: BM=64 x BN=256 tiles, 256-thread blocks (4 waves), 1 barrier/K-step,
//     transposed conflict-free LDS (lane=row staging), acc=64 VGPR -> 4 blocks/CU.

#define NTA   65536
#define DIM_O 512
#define NMAXD 512
#define NSPE  4
#define BM    64
#define BK    64

typedef __attribute__((ext_vector_type(4))) float  f32x4;
typedef __attribute__((ext_vector_type(8))) short  bf16x8;

__device__ __forceinline__ short f2bf(float f) {
    unsigned u = __builtin_bit_cast(unsigned, f);
    u += 0x7FFFu + ((u >> 16) & 1u);
    return (short)(u >> 16);
}

__global__ void build_lists_kernel(const int* __restrict__ sym,
                                   int* __restrict__ counts,
                                   int* __restrict__ lists) {
    int i = blockIdx.x * 256 + threadIdx.x;
    int s = sym[i];
    int lane = threadIdx.x & 63;
    #pragma unroll
    for (int spe = 0; spe < NSPE; ++spe) {
        unsigned long long m = __ballot(s == spe);
        if (m == 0ull) continue;
        int leader = __ffsll(m) - 1;
        int base = 0;
        if (lane == leader) base = atomicAdd(&counts[spe], __popcll(m));
        base = __shfl(base, leader);
        if (s == spe) {
            int pos = __popcll(m & ((1ull << lane) - 1ull));
            lists[spe * NTA + base + pos] = i;
        }
    }
}

// Pack W[s][k][n] (fp32) -> bf16 MFMA-B fragment layout:
// Wp[((s*16+kb)*32+nb)*512 + lane*8 + j] = bf16(W[s][kb*32+(lane>>4)*8+j][nb*16+(lane&15)])
__global__ void pack_w_kernel(const float* __restrict__ W, short* __restrict__ Wp) {
    int idx = blockIdx.x * 256 + threadIdx.x;
    int j  = idx & 7;
    int l  = (idx >> 3) & 63;
    int nb = (idx >> 9) & 31;
    int kb = (idx >> 14) & 15;
    int s  = idx >> 18;
    int k = kb * 32 + (l >> 4) * 8 + j;
    int n = nb * 16 + (l & 15);
    Wp[idx] = f2bf(W[((size_t)s * DIM_O + k) * NMAXD + n]);
}

// LDS A layout: 16B slot index = chunk*64 + row, chunk = k-elems [8c, 8c+8).
// Staging: lane = row, wave w stages k-quarter [w*16, w*16+16) -> chunks 2w, 2w+1.
// Both ds_write and ds_read hit bank-quad (row % 8): 2-way per 16-lane phase (free).
__global__ __launch_bounds__(256, 4)
void gemm_kernel(const float* __restrict__ rho,
                 const short* __restrict__ Wp,
                 const float* __restrict__ bias,
                 const int*  __restrict__ counts,
                 const int*  __restrict__ lists,
                 float* __restrict__ out)
{
    const int s   = blockIdx.x & 3;
    const int ch  = (blockIdx.x >> 2) & 1;   // N half: cols [ch*256, ch*256+256)
    const int mb  = blockIdx.x >> 3;
    const int cnt = counts[s];
    const int row0 = mb * BM;
    if (row0 >= cnt) return;
    int rows_here = cnt - row0; if (rows_here > BM) rows_here = BM;

    __shared__ int aidx[BM];
    __shared__ __align__(16) short Abuf[2][8 * 64 * 8];  // 2 x 8KB

    const int tid  = threadIdx.x;
    const int lane = tid & 63;
    const int w    = tid >> 6;            // wave id 0..3, owns cols w*64..w*64+64
    const int lrow = lane & 15;
    const int lgr  = lane >> 4;

    if (tid < BM)
        aidx[tid] = lists[s * NTA + row0 + ((tid < rows_here) ? tid : 0)];
    __syncthreads();

    const float* gsrc = rho + (size_t)aidx[lane] * DIM_O + w * 16;
    const short* wbase = Wp + ((size_t)s * 512 + ch * 16 + w * 4) * 512 + lane * 8;

    f32x4 acc[4][4];
    #pragma unroll
    for (int m = 0; m < 4; ++m)
        #pragma unroll
        for (int n = 0; n < 4; ++n) acc[m][n] = (f32x4)0.0f;

    f32x4 st[4];
    // prologue: stage K-step 0
    { const f32x4* p = (const f32x4*)gsrc; st[0]=p[0]; st[1]=p[1]; st[2]=p[2]; st[3]=p[3]; }
    {
        short tmp[16];
        #pragma unroll
        for (int i = 0; i < 4; ++i)
            #pragma unroll
            for (int q = 0; q < 4; ++q) tmp[i*4+q] = f2bf(st[i][q]);
        *(bf16x8*)&Abuf[0][((2*w    )*64 + lane)*8] = *(const bf16x8*)&tmp[0];
        *(bf16x8*)&Abuf[0][((2*w + 1)*64 + lane)*8] = *(const bf16x8*)&tmp[8];
    }
    __syncthreads();

    for (int kt = 0; kt < 8; ++kt) {
        const int buf = kt & 1;
        if (kt < 7) {  // issue next K-step's global loads early (latency hides under MFMA)
            const f32x4* p = (const f32x4*)(gsrc + (kt + 1) * BK);
            st[0]=p[0]; st[1]=p[1]; st[2]=p[2]; st[3]=p[3];
        }
        #pragma unroll
        for (int ks = 0; ks < 2; ++ks) {
            const int kb = kt * 2 + ks;
            bf16x8 bfrag[4];
            #pragma unroll
            for (int nf = 0; nf < 4; ++nf)
                bfrag[nf] = *(const bf16x8*)(wbase + (size_t)(kb * 32 + nf) * 512);
            #pragma unroll
            for (int mf = 0; mf < 4; ++mf) {
                const bf16x8 afrag =
                    *(const bf16x8*)&Abuf[buf][((ks*4 + lgr)*64 + mf*16 + lrow)*8];
                #pragma unroll
                for (int nf = 0; nf < 4; ++nf)
                    acc[mf][nf] = __builtin_amdgcn_mfma_f32_16x16x32_bf16(
                        afrag, bfrag[nf], acc[mf][nf], 0, 0, 0);
            }
        }
        if (kt < 7) {
            short tmp[16];
            #pragma unroll
            for (int i = 0; i < 4; ++i)
                #pragma unroll
                for (int q = 0; q < 4; ++q) tmp[i*4+q] = f2bf(st[i][q]);
            short* base = Abuf[buf ^ 1];
            *(bf16x8*)&base[((2*w    )*64 + lane)*8] = *(const bf16x8*)&tmp[0];
            *(bf16x8*)&base[((2*w + 1)*64 + lane)*8] = *(const bf16x8*)&tmp[8];
            __syncthreads();
        }
    }

    // epilogue: bias + per-row store (16 lanes write 64B contiguous per row)
    float bv[4];
    #pragma unroll
    for (int nf = 0; nf < 4; ++nf)
        bv[nf] = bias[s * NMAXD + ch * 256 + w * 64 + nf * 16 + lrow];
    #pragma unroll
    for (int mf = 0; mf < 4; ++mf) {
        #pragma unroll
        for (int q = 0; q < 4; ++q) {
            const int r = mf * 16 + lgr * 4 + q;
            if (r < rows_here) {
                float* orow = out + (size_t)aidx[r] * NMAXD + ch * 256 + w * 64 + lrow;
                #pragma unroll
                for (int nf = 0; nf < 4; ++nf)
                    orow[nf * 16] = acc[mf][nf][q] + bv[nf];
            }
        }
    }
}

extern "C" void kernel_launch(void* const* d_in, const int* in_sizes, int n_in,
                              void* d_out, int out_size, void* d_ws, size_t ws_size,
                              hipStream_t stream) {
    const float* rho = (const float*)d_in[0];
    const float* W   = (const float*)d_in[1];
    const float* b   = (const float*)d_in[2];
    const int*   sym = (const int*)d_in[3];
    float* out = (float*)d_out;

    int*   counts = (int*)d_ws;
    int*   lists  = (int*)((char*)d_ws + 1024);
    short* Wp     = (short*)((char*)d_ws + 1024 + (size_t)NSPE * NTA * 4);

    hipMemsetAsync(counts, 0, NSPE * sizeof(int), stream);
    build_lists_kernel<<<NTA / 256, 256, 0, stream>>>(sym, counts, lists);
    pack_w_kernel<<<(NSPE * DIM_O * NMAXD) / 256, 256, 0, stream>>>(W, Wp);
    gemm_kernel<<<NSPE * 2 * (NTA / BM), 256, 0, stream>>>(rho, Wp, b, counts, lists, out);
}

// Round 3
// 132.183 us; speedup vs baseline: 1.1266x; 1.1266x over previous
//
#include <hip/hip_runtime.h>

// Species-routed expert Linear as a bucketed grouped GEMM.
//   out[a] = rho[a] @ W[sym[a]] + b[sym[a]]   (NTA=65536, K=N=512, 4 species)
// R3: BM=64 x BN=512 (full N, rho read once), 512 threads (8 waves),
//     MERGED-request A staging: 8 consecutive lanes read 128 B contiguous of
//     one row (requests coalesce 4x vs R1/R2's scatter), double-buffered LDS,
//     1 barrier/K-step, conflict-free LDS read layout (measured 0 in R2).

#define NTA   65536
#define DIM_O 512
#define NMAXD 512
#define NSPE  4
#define BM    64
#define BK    64

typedef __attribute__((ext_vector_type(4))) float  f32x4;
typedef __attribute__((ext_vector_type(8))) short  bf16x8;
typedef __attribute__((ext_vector_type(4))) short  bf16x4;

__device__ __forceinline__ short f2bf(float f) {
    unsigned u = __builtin_bit_cast(unsigned, f);
    u += 0x7FFFu + ((u >> 16) & 1u);
    return (short)(u >> 16);
}

__global__ void build_lists_kernel(const int* __restrict__ sym,
                                   int* __restrict__ counts,
                                   int* __restrict__ lists) {
    int i = blockIdx.x * 256 + threadIdx.x;
    int s = sym[i];
    int lane = threadIdx.x & 63;
    #pragma unroll
    for (int spe = 0; spe < NSPE; ++spe) {
        unsigned long long m = __ballot(s == spe);
        if (m == 0ull) continue;
        int leader = __ffsll(m) - 1;
        int base = 0;
        if (lane == leader) base = atomicAdd(&counts[spe], __popcll(m));
        base = __shfl(base, leader);
        if (s == spe) {
            int pos = __popcll(m & ((1ull << lane) - 1ull));
            lists[spe * NTA + base + pos] = i;
        }
    }
}

// Pack W[s][k][n] (fp32) -> bf16 MFMA-B fragment layout:
// Wp[((s*16+kb)*32+nb)*512 + lane*8 + j] = bf16(W[s][kb*32+(lane>>4)*8+j][nb*16+(lane&15)])
__global__ void pack_w_kernel(const float* __restrict__ W, short* __restrict__ Wp) {
    int idx = blockIdx.x * 256 + threadIdx.x;
    int j  = idx & 7;
    int l  = (idx >> 3) & 63;
    int nb = (idx >> 9) & 31;
    int kb = (idx >> 14) & 15;
    int s  = idx >> 18;
    int k = kb * 32 + (l >> 4) * 8 + j;
    int n = nb * 16 + (l & 15);
    Wp[idx] = f2bf(W[((size_t)s * DIM_O + k) * NMAXD + n]);
}

// LDS A layout: 16B slot = chunk*64 + row, chunk = k-floats [8c, 8c+8).
// Staging: thread t -> row t>>3, k-chunk4 (t&7)*4 within each 32-float half;
//   8 consecutive lanes read 128 B CONTIGUOUS of one row -> requests merge.
// Read: afrag = slot(chunk ks*4+lgr, row mf*16+lrow) -> measured 0 conflicts.
__global__ __launch_bounds__(512, 4)
void gemm_kernel(const float* __restrict__ rho,
                 const short* __restrict__ Wp,
                 const float* __restrict__ bias,
                 const int*  __restrict__ counts,
                 const int*  __restrict__ lists,
                 float* __restrict__ out)
{
    const int s   = blockIdx.x & 3;
    const int mb  = blockIdx.x >> 2;
    const int cnt = counts[s];
    const int row0 = mb * BM;
    if (row0 >= cnt) return;
    int rows_here = cnt - row0; if (rows_here > BM) rows_here = BM;

    __shared__ int aidx[BM];
    __shared__ __align__(16) short Abuf[2][8 * 64 * 8];  // 2 x 8 KB

    const int tid  = threadIdx.x;
    const int lane = tid & 63;
    const int w    = tid >> 6;            // wave 0..7 owns cols [w*64, w*64+64)
    const int lrow = lane & 15;
    const int lgr  = lane >> 4;

    if (tid < BM)
        aidx[tid] = lists[s * NTA + row0 + ((tid < rows_here) ? tid : 0)];
    __syncthreads();

    // merged staging addresses
    const int srow  = tid >> 3;
    const int scol8 = tid & 7;
    const float* gsrc = rho + (size_t)aidx[srow] * DIM_O + scol8 * 4;
    // LDS dst offsets (shorts) for round r: ((r*4 + (scol8>>1))*64 + srow)*8 + (scol8&1)*4
    const int dso0 = (((scol8 >> 1)    ) * 64 + srow) * 8 + (scol8 & 1) * 4;
    const int dso1 = (((scol8 >> 1) + 4) * 64 + srow) * 8 + (scol8 & 1) * 4;

    const short* wbase = Wp + ((size_t)s * 512 + w * 4) * 512 + lane * 8;

    f32x4 acc[4][4];
    #pragma unroll
    for (int m = 0; m < 4; ++m)
        #pragma unroll
        for (int n = 0; n < 4; ++n) acc[m][n] = (f32x4)0.0f;

    f32x4 st0, st1;
    // prologue: stage K-step 0
    st0 = *(const f32x4*)(gsrc);
    st1 = *(const f32x4*)(gsrc + 32);
    {
        bf16x4 a, b;
        #pragma unroll
        for (int q = 0; q < 4; ++q) { a[q] = f2bf(st0[q]); b[q] = f2bf(st1[q]); }
        *(bf16x4*)&Abuf[0][dso0] = a;
        *(bf16x4*)&Abuf[0][dso1] = b;
    }
    __syncthreads();

    for (int kt = 0; kt < 8; ++kt) {
        const int buf = kt & 1;
        if (kt < 7) {  // issue next K-step's loads early; latency hides under MFMA
            st0 = *(const f32x4*)(gsrc + (kt + 1) * BK);
            st1 = *(const f32x4*)(gsrc + (kt + 1) * BK + 32);
        }
        #pragma unroll
        for (int ks = 0; ks < 2; ++ks) {
            const int kb = kt * 2 + ks;
            bf16x8 bfrag[4];
            #pragma unroll
            for (int nf = 0; nf < 4; ++nf)
                bfrag[nf] = *(const bf16x8*)(wbase + (size_t)(kb * 32 + nf) * 512);
            #pragma unroll
            for (int mf = 0; mf < 4; ++mf) {
                const bf16x8 afrag =
                    *(const bf16x8*)&Abuf[buf][((ks * 4 + lgr) * 64 + mf * 16 + lrow) * 8];
                #pragma unroll
                for (int nf = 0; nf < 4; ++nf)
                    acc[mf][nf] = __builtin_amdgcn_mfma_f32_16x16x32_bf16(
                        afrag, bfrag[nf], acc[mf][nf], 0, 0, 0);
            }
        }
        if (kt < 7) {
            bf16x4 a, b;
            #pragma unroll
            for (int q = 0; q < 4; ++q) { a[q] = f2bf(st0[q]); b[q] = f2bf(st1[q]); }
            short* base = Abuf[buf ^ 1];
            *(bf16x4*)&base[dso0] = a;
            *(bf16x4*)&base[dso1] = b;
            __syncthreads();
        }
    }

    // epilogue: bias + per-row store (16 lanes write 64 B contiguous per row)
    float bv[4];
    #pragma unroll
    for (int nf = 0; nf < 4; ++nf)
        bv[nf] = bias[s * NMAXD + w * 64 + nf * 16 + lrow];
    #pragma unroll
    for (int mf = 0; mf < 4; ++mf) {
        #pragma unroll
        for (int q = 0; q < 4; ++q) {
            const int r = mf * 16 + lgr * 4 + q;
            if (r < rows_here) {
                float* orow = out + (size_t)aidx[r] * NMAXD + w * 64 + lrow;
                #pragma unroll
                for (int nf = 0; nf < 4; ++nf)
                    orow[nf * 16] = acc[mf][nf][q] + bv[nf];
            }
        }
    }
}

extern "C" void kernel_launch(void* const* d_in, const int* in_sizes, int n_in,
                              void* d_out, int out_size, void* d_ws, size_t ws_size,
                              hipStream_t stream) {
    const float* rho = (const float*)d_in[0];
    const float* W   = (const float*)d_in[1];
    const float* b   = (const float*)d_in[2];
    const int*   sym = (const int*)d_in[3];
    float* out = (float*)d_out;

    int*   counts = (int*)d_ws;
    int*   lists  = (int*)((char*)d_ws + 1024);
    short* Wp     = (short*)((char*)d_ws + 1024 + (size_t)NSPE * NTA * 4);

    hipMemsetAsync(counts, 0, NSPE * sizeof(int), stream);
    build_lists_kernel<<<NTA / 256, 256, 0, stream>>>(sym, counts, lists);
    pack_w_kernel<<<(NSPE * DIM_O * NMAXD) / 256, 256, 0, stream>>>(W, Wp);
    gemm_kernel<<<NSPE * (NTA / BM), 512, 0, stream>>>(rho, Wp, b, counts, lists, out);
}